// Round 25
// baseline (57.159 us; speedup 1.0000x reference)
//
#include <hip/hip_runtime.h>
#include <hip/hip_bf16.h>
#include <hip/hip_fp8.h>
#include <math.h>

#define BB 8192
#define XD 784
#define ZD 10
#define KK 2000
#define HH 300
#define LOG2E 1.4426950408889634f
#define LN2   0.6931471805599453f

typedef unsigned char uchar16 __attribute__((ext_vector_type(16)));
typedef long lng2 __attribute__((ext_vector_type(2)));
typedef float f32x4 __attribute__((ext_vector_type(4)));

__device__ __forceinline__ float sp_(float x) {
    return fmaxf(x, 0.f) + __logf(1.f + __expf(-fabsf(x)));
}
__device__ __forceinline__ float elu_(float x) { return x > 0.f ? x : __expf(x) - 1.f; }
// packed fp8 converts: hiw must be an IMMEDIATE -> template constant (r24 fix)
template<bool HI>
__device__ __forceinline__ unsigned int pk2_(float a, float b, unsigned int old) {
    return __builtin_amdgcn_cvt_pk_fp8_f32(a, b, old, HI);
}
__device__ __forceinline__ unsigned int pk4_(float a, float b, float c, float d) {
    return pk2_<true>(c, d, pk2_<false>(a, b, 0u));
}
__device__ __forceinline__ unsigned char f8_(float v) {
    __hip_fp8_e4m3 t(v);
    return (unsigned char)t.__x;
}
__device__ __forceinline__ uchar16 ld16_(const unsigned char* p) {
    return *reinterpret_cast<const uchar16*>(p);
}
// fp8 MFMA over one 16B chunk pair (K=64)
__device__ __forceinline__ void mm64(f32x4& acc, uchar16 a, uchar16 b) {
    lng2 la = __builtin_bit_cast(lng2, a);
    lng2 lb = __builtin_bit_cast(lng2, b);
    acc = __builtin_amdgcn_mfma_f32_16x16x32_fp8_fp8(la[0], lb[0], acc, 0, 0, 0);
    acc = __builtin_amdgcn_mfma_f32_16x16x32_fp8_fp8(la[1], lb[1], acc, 0, 0, 0);
}
// fp8 fragment-major byte index: chunk base + element (row<16, k)
__device__ __forceinline__ int fpi_(int chunk, int row, int k) {
    return ((chunk + (k >> 6)) * 64 + row + (((k >> 3) & 3) << 4)) * 16
           + (k & 7) + (((k >> 5) & 1) << 3);
}

// ---------------------------------------------------------------------------
// 16-wave fp8 register-streamed layer (r23 structure).
// ---------------------------------------------------------------------------
template<int LMODE, int KP, int NI>
__device__ __forceinline__ void layerRf(
    const int tid,
    const unsigned char* __restrict__ actin,
    const unsigned char* __restrict__ Wt,
    const float* __restrict__ bias,
    unsigned char* __restrict__ actout,
    float* __restrict__ c3L, float* __restrict__ redL,
    const float* __restrict__ xrow, float INV, float OUTS)
{
    const int w = tid >> 6, l = tid & 63;
    const int wl = w & 7, wh = w >> 3;
    const int cl = l & 15, hi = l >> 4, g4 = hi << 2;
    constexpr int KS = KP / 64;
    constexpr int NJ = (NI + 1) / 2;
    constexpr int NP = (NJ + 1) / 2;
    const unsigned char* bsrc = Wt + l * 16;

    float rA[2][4];
    #pragma unroll
    for (int rg = 0; rg < 2; ++rg)
        #pragma unroll
        for (int rr = 0; rr < 4; ++rr) rA[rg][rr] = 0.f;

    #pragma unroll
    for (int p = 0; p < NP; ++p) {
        f32x4 acc[2][2];
        #pragma unroll
        for (int j = 0; j < 2; ++j)
            #pragma unroll
            for (int rg = 0; rg < 2; ++rg) acc[j][rg] = (f32x4){0.f, 0.f, 0.f, 0.f};

        int niC[2], rawv[2];
        #pragma unroll
        for (int j = 0; j < 2; ++j) {
            const int njIdx = 2 * p + j;
            const int raw = (njIdx < NJ) ? (2 * njIdx + wh) : (NI - 1);
            rawv[j] = (njIdx < NJ) ? (2 * njIdx + wh) : NI;
            niC[j] = (raw < NI) ? raw : (NI - 1);
        }

        uchar16 Bb[2][2];
        #pragma unroll
        for (int j = 0; j < 2; ++j)
            if ((2 * p + j) < NJ)
                Bb[0][j] = ld16_(bsrc + (((size_t)(niC[j] * 8 + wl) * KS) << 10));

        #pragma unroll
        for (int ki = 0; ki < KS; ++ki) {
            const int cur = ki & 1, nxt = cur ^ 1;
            if (ki + 1 < KS) {
                #pragma unroll
                for (int j = 0; j < 2; ++j)
                    if ((2 * p + j) < NJ)
                        Bb[nxt][j] = ld16_(bsrc + (((size_t)(niC[j] * 8 + wl) * KS + ki + 1) << 10));
            }
            uchar16 a[2];
            a[0] = ld16_(actin + ((0 * KS + ki) * 64 + l) * 16);
            a[1] = ld16_(actin + ((1 * KS + ki) * 64 + l) * 16);
            #pragma unroll
            for (int j = 0; j < 2; ++j)
                if ((2 * p + j) < NJ)
                    #pragma unroll
                    for (int rg = 0; rg < 2; ++rg)
                        mm64(acc[j][rg], a[rg], Bb[cur][j]);
        }

        #pragma unroll
        for (int j = 0; j < 2; ++j) {
            if ((2 * p + j) >= NJ) continue;
            const bool act = rawv[j] < NI;
            const int c = rawv[j] * 128 + wl * 16 + cl;
            if constexpr (LMODE == 0) {
                const float bb = (act && c < HH) ? bias[c] : 0.f;
                #pragma unroll
                for (int rg = 0; rg < 2; ++rg)
                    #pragma unroll
                    for (int rr = 0; rr < 4; ++rr) {
                        float o = (c < HH) ? elu_(acc[j][rg][rr] * INV + bb) : 0.f;
                        if (act && c < 320)
                            actout[fpi_(rg * 5, g4 + rr, c)] = f8_(o * OUTS);
                    }
            } else if constexpr (LMODE == 1) {
                const int cc = wl * 16 + cl;
                if (act && cc < 20) {
                    #pragma unroll
                    for (int rg = 0; rg < 2; ++rg)
                        #pragma unroll
                        for (int rr = 0; rr < 4; ++rr)
                            c3L[(rg * 16 + g4 + rr) * 24 + cc] = acc[j][rg][rr] * INV + bias[cc];
                }
            } else {
                if (act && c < XD) {
                    const float bb = bias[c];
                    #pragma unroll
                    for (int rg = 0; rg < 2; ++rg)
                        #pragma unroll
                        for (int rr = 0; rr < 4; ++rr) {
                            float lv = acc[j][rg][rr] * INV + bb;
                            float xv = xrow[(size_t)(rg * 16 + g4 + rr) * XD + c];
                            rA[rg][rr] += xv * lv - sp_(lv);
                        }
                }
            }
        }
    }

    if constexpr (LMODE == 2) {
        #pragma unroll
        for (int rg = 0; rg < 2; ++rg)
            #pragma unroll
            for (int rr = 0; rr < 4; ++rr) {
                float s = rA[rg][rr];
                s += __shfl_xor(s, 1); s += __shfl_xor(s, 2);
                s += __shfl_xor(s, 4); s += __shfl_xor(s, 8);
                if (cl == 0) redL[(rg * 16 + g4 + rr) * 16 + w] = s;
            }
    }
}

// ---------------------------------------------------------------------------
// comp in BASE-2 with PARITY-SPLIT online accumulators (halved dep chain);
// exp2f/log2f map 1:1 to v_exp/v_log. redM/redS in base-2.
// ---------------------------------------------------------------------------
__device__ __forceinline__ void layerCf(
    const int tid,
    const unsigned char* __restrict__ fbL,
    const unsigned char* __restrict__ G,
    const float* __restrict__ cb2,
    float* __restrict__ redM, float* __restrict__ redS)
{
    const int w = tid >> 6, l = tid & 63;
    const int wl = w & 7, wh = w >> 3;
    const int cl = l & 15, hi = l >> 4, g4 = hi << 2;
    const unsigned char* bsrc = G + l * 16;
    const float INV2 = (1.f / 256.f) * LOG2E;

    uchar16 a[2];
    a[0] = ld16_(fbL + (0 * 64 + l) * 16);
    a[1] = ld16_(fbL + (1 * 64 + l) * 16);

    float mA[2][2][4], sA[2][2][4];   // [parity][rg][rr]
    #pragma unroll
    for (int pa = 0; pa < 2; ++pa)
        #pragma unroll
        for (int rg = 0; rg < 2; ++rg)
            #pragma unroll
            for (int rr = 0; rr < 4; ++rr) { mA[pa][rg][rr] = -1e30f; sA[pa][rg][rr] = 0.f; }

    uchar16 c0 = ld16_(bsrc + (((size_t)(wh * 8 + wl)) << 10));
    #pragma unroll
    for (int nj = 0; nj < 8; ++nj) {
        uchar16 p0 = c0;
        if (nj + 1 < 8)
            p0 = ld16_(bsrc + (((size_t)((2 * (nj + 1) + wh) * 8 + wl)) << 10));
        const int c = ((2 * nj + wh) * 8 + wl) * 16 + cl;
        const float cb = cb2[c];
        const int pa = nj & 1;
        f32x4 acc[2];
        #pragma unroll
        for (int rg = 0; rg < 2; ++rg) {
            acc[rg] = (f32x4){0.f, 0.f, 0.f, 0.f};
            mm64(acc[rg], a[rg], c0);
        }
        #pragma unroll
        for (int rg = 0; rg < 2; ++rg)
            #pragma unroll
            for (int rr = 0; rr < 4; ++rr) {
                float v = acc[rg][rr] * INV2 + cb;
                float mx = fmaxf(v, mA[pa][rg][rr]);
                sA[pa][rg][rr] = sA[pa][rg][rr] * exp2f(mA[pa][rg][rr] - mx) + exp2f(v - mx);
                mA[pa][rg][rr] = mx;
            }
        c0 = p0;
    }
    // merge parities
    float rA[2][4], rB[2][4];
    #pragma unroll
    for (int rg = 0; rg < 2; ++rg)
        #pragma unroll
        for (int rr = 0; rr < 4; ++rr) {
            float M = fmaxf(mA[0][rg][rr], mA[1][rg][rr]);
            rB[rg][rr] = sA[0][rg][rr] * exp2f(mA[0][rg][rr] - M)
                       + sA[1][rg][rr] * exp2f(mA[1][rg][rr] - M);
            rA[rg][rr] = M;
        }
    #pragma unroll
    for (int d = 1; d <= 8; d <<= 1)
        #pragma unroll
        for (int rg = 0; rg < 2; ++rg)
            #pragma unroll
            for (int rr = 0; rr < 4; ++rr) {
                float mo = __shfl_xor(rA[rg][rr], d);
                float so = __shfl_xor(rB[rg][rr], d);
                float M = fmaxf(rA[rg][rr], mo);
                rB[rg][rr] = rB[rg][rr] * exp2f(rA[rg][rr] - M) + so * exp2f(mo - M);
                rA[rg][rr] = M;
            }
    if (cl == 0) {
        #pragma unroll
        for (int rg = 0; rg < 2; ++rg)
            #pragma unroll
            for (int rr = 0; rr < 4; ++rr) {
                redM[(rg * 16 + g4 + rr) * 16 + w] = rA[rg][rr];
                redS[(rg * 16 + g4 + rr) * 16 + w] = rB[rg][rr];
            }
    }
}

__global__ __launch_bounds__(1024, 1)
void fused_k(const float* __restrict__ xg,
             const unsigned char* __restrict__ w1t, const float* __restrict__ eb1,
             const unsigned char* __restrict__ w2t, const float* __restrict__ eb2,
             const unsigned char* __restrict__ w3t, const float* __restrict__ eb3,
             const unsigned char* __restrict__ d1t, const float* __restrict__ db1,
             const unsigned char* __restrict__ d2t, const float* __restrict__ db2,
             const unsigned char* __restrict__ d3t, const float* __restrict__ db3,
             const unsigned char* __restrict__ G, const float* __restrict__ cb2,
             const float* __restrict__ eps, float* __restrict__ part)
{
    __shared__ __align__(16) unsigned char xsf8[26624];  // 32x832 fp8 frag-major
    __shared__ __align__(16) unsigned char actP[10240];
    __shared__ __align__(16) unsigned char actQ[10240];
    __shared__ __align__(16) unsigned char fbL[2048];
    __shared__ float uredc[1568];

    float* c3L  = uredc;
    float* redM = uredc;
    float* redS = uredc + 512;
    float* redL = uredc + 1024;
    float* lqzL = uredc + 1536;

    const int tid = threadIdx.x;
    const int m0 = blockIdx.x * 32;

    // stage x slab fp32 -> fp8 (x16) into LDS (packed converts)
    #pragma unroll
    for (int it = 0; it < 2; ++it) {
        const int c = tid + it * 1024;
        if (c < 26 * 64) {
            const int chunk = c >> 6, lane = c & 63;
            const int rg = chunk / 13, kc = chunk % 13;
            const int row = m0 + rg * 16 + (lane & 15);
            const int h2 = lane >> 4;
            uint4 u;
            unsigned int* up = &u.x;
            #pragma unroll
            for (int half = 0; half < 2; ++half) {
                const int kb = kc * 64 + half * 32 + h2 * 8;
                float f[8];
                if (kb + 7 < XD) {
                    float4 f0 = *reinterpret_cast<const float4*>(&xg[(size_t)row * XD + kb]);
                    float4 f1 = *reinterpret_cast<const float4*>(&xg[(size_t)row * XD + kb + 4]);
                    f[0] = f0.x; f[1] = f0.y; f[2] = f0.z; f[3] = f0.w;
                    f[4] = f1.x; f[5] = f1.y; f[6] = f1.z; f[7] = f1.w;
                } else {
                    #pragma unroll
                    for (int e = 0; e < 8; ++e) {
                        const int k = kb + e;
                        f[e] = (k < XD) ? xg[(size_t)row * XD + k] : 0.f;
                    }
                }
                up[half * 2 + 0] = pk4_(f[0] * 16.f, f[1] * 16.f, f[2] * 16.f, f[3] * 16.f);
                up[half * 2 + 1] = pk4_(f[4] * 16.f, f[5] * 16.f, f[6] * 16.f, f[7] * 16.f);
            }
            *reinterpret_cast<uint4*>(&xsf8[c * 16]) = u;
        }
    }
    // zero ALL of fbL: sizeof(fbL)=2048B = 128 uint4
    if (tid < 128) reinterpret_cast<uint4*>(fbL)[tid] = (uint4){0u, 0u, 0u, 0u};
    __syncthreads();

    layerRf<0, 832, 3>(tid, xsf8, w1t, eb1, actP, nullptr, nullptr, nullptr,
                       1.f / 1024.f, 16.f);
    __syncthreads();
    layerRf<0, 320, 3>(tid, actP, w2t, eb2, actQ, nullptr, nullptr, nullptr,
                       1.f / 1024.f, 16.f);
    __syncthreads();
    layerRf<1, 320, 1>(tid, actQ, w3t, eb3, nullptr, c3L, nullptr, nullptr,
                       1.f / 1024.f, 0.f);
    __syncthreads();

    if (tid < 32) {
        float a = 0.f;
        const int rg = tid >> 4, rl = tid & 15;
        #pragma unroll
        for (int j = 0; j < ZD; ++j) {
            float qm = c3L[tid * 24 + j];
            float qh = c3L[tid * 24 + 10 + j];
            float qv = sp_(qh) + 1e-8f;
            float e  = eps[(size_t)(m0 + tid) * ZD + j];
            float zj = qm + sqrtf(qv) * e;
            fbL[fpi_(rg, rl, j)]      = f8_(zj * zj * 4.f);
            fbL[fpi_(rg, rl, 10 + j)] = f8_(zj * 4.f);
            float d = zj - qm;
            a += __logf(6.283185307179586f * qv) + d * d / qv;
        }
        lqzL[tid] = -0.5f * a;
    }
    __syncthreads();

    layerRf<0, 64, 3>(tid, fbL, d1t, db1, actP, nullptr, nullptr, nullptr,
                      1.f / 64.f, 16.f);
    __syncthreads();
    layerRf<0, 320, 3>(tid, actP, d2t, db2, actQ, nullptr, nullptr, nullptr,
                       1.f / 1024.f, 16.f);
    __syncthreads();
    layerRf<2, 320, 7>(tid, actQ, d3t, db3, nullptr, nullptr, redL,
                       xg + (size_t)m0 * XD, 1.f / 1024.f, 0.f);
    __syncthreads();
    layerCf(tid, fbL, G, cb2, redM, redS);
    __syncthreads();

    if (tid < 32) {
        float M = -1e30f, S = 0.f;
        #pragma unroll
        for (int w16 = 0; w16 < 16; ++w16) {
            float m = redM[tid * 16 + w16], s = redS[tid * 16 + w16];
            float M2 = fmaxf(M, m);
            S = S * exp2f(M - M2) + s * exp2f(m - M2);
            M = M2;
        }
        // base-2 -> natural: lpz = ln2*(M + log2(S)) - log(2000)
        float lpz = LN2 * (M + log2f(S)) - 7.6009024595420824f;
        float lpx = 0.f;
        #pragma unroll
        for (int w16 = 0; w16 < 16; ++w16) lpx += redL[tid * 16 + w16];
        float kl = lqzL[tid] - lpz;
        float ne = kl - lpx, re = -lpx;
        #pragma unroll
        for (int d = 1; d <= 16; d <<= 1) {
            ne += __shfl_xor(ne, d); kl += __shfl_xor(kl, d); re += __shfl_xor(re, d);
        }
        if (tid == 0) {
            part[blockIdx.x * 3 + 0] = ne;
            part[blockIdx.x * 3 + 1] = kl;
            part[blockIdx.x * 3 + 2] = re;
        }
    }
}

// ---------------------------------------------------------------------------
// prep: weights -> fp8 fragment-major (scaled); G (x64) + cb2 = cbias*log2e.
// ---------------------------------------------------------------------------
__global__ __launch_bounds__(256)
void prep_k(const float* __restrict__ ew1, const float* __restrict__ ew2,
            const float* __restrict__ ew3, const float* __restrict__ dw1,
            const float* __restrict__ dw2, const float* __restrict__ dw3,
            const float* __restrict__ zpre,
            unsigned char* __restrict__ w1t, unsigned char* __restrict__ w2t,
            unsigned char* __restrict__ w3t, unsigned char* __restrict__ d1t,
            unsigned char* __restrict__ d2t, unsigned char* __restrict__ d3t,
            unsigned char* __restrict__ G, float* __restrict__ cb2)
{
    const int t = blockIdx.x * 256 + threadIdx.x;
    const int y = blockIdx.y;
    const int lane = t & 63, chunk = t >> 6;
    const int cl = lane & 15, hi = lane >> 4;

    auto genw = [&](const float* W, unsigned char* out, int NT, int KS,
                    int K, int N, float s) {
        if (chunk >= NT * KS) return;
        const int kc = chunk % KS, nt = chunk / KS;
        const int n = nt * 16 + cl;
        uchar16 v;
        #pragma unroll
        for (int e = 0; e < 16; ++e) {
            const int k = kc * 64 + (e >> 3) * 32 + hi * 8 + (e & 7);
            v[e] = f8_((n < N && k < K) ? W[(size_t)k * N + n] * s : 0.f);
        }
        *reinterpret_cast<uchar16*>(&out[(size_t)t * 16]) = v;
    };

    if (y == 0) genw(ew1, w1t, 24, 13, XD, HH, 64.f);
    else if (y == 1) genw(ew2, w2t, 24, 5, HH, HH, 64.f);
    else if (y == 2) genw(ew3, w3t, 8, 5, HH, 2 * ZD, 64.f);
    else if (y == 3) {
        if (chunk >= 24) return;
        const int n = chunk * 16 + cl;
        uchar16 v;
        #pragma unroll
        for (int e = 0; e < 16; ++e) {
            const int k = (e >> 3) * 32 + hi * 8 + (e & 7);
            float vv = (n < HH && k >= 10 && k < 20) ? dw1[(size_t)(k - 10) * HH + n] * 16.f : 0.f;
            v[e] = f8_(vv);
        }
        *reinterpret_cast<uchar16*>(&d1t[(size_t)t * 16]) = v;
    }
    else if (y == 4) genw(dw2, d2t, 24, 5, HH, HH, 64.f);
    else if (y == 5) genw(dw3, d3t, 56, 5, HH, XD, 64.f);
    else {
        if (chunk >= 128) return;
        const int n = chunk * 16 + cl;
        uchar16 v;
        #pragma unroll
        for (int e = 0; e < 16; ++e) {
            const int k = (e >> 3) * 32 + hi * 8 + (e & 7);
            float vv = 0.f;
            if (n < KK) {
                if (k < 10) {
                    float h = zpre[(KK + n) * ZD + k];
                    float vr = sp_(h) + 1e-8f;
                    vv = (-0.5f / vr) * 64.f;
                } else if (k < 20) {
                    float m = zpre[n * ZD + (k - 10)];
                    float h = zpre[(KK + n) * ZD + (k - 10)];
                    float vr = sp_(h) + 1e-8f;
                    vv = (m / vr) * 64.f;
                }
            }
            v[e] = f8_(vv);
        }
        *reinterpret_cast<uchar16*>(&G[(size_t)t * 16]) = v;
        if (hi == 0) {
            float cb = -1e30f;
            if (n < KK) {
                float csum = 0.f;
                #pragma unroll
                for (int j = 0; j < ZD; ++j) {
                    float m = zpre[n * ZD + j];
                    float h = zpre[(KK + n) * ZD + j];
                    float vr = sp_(h) + 1e-8f;
                    csum += __logf(6.283185307179586f * vr) + m * m / vr;
                }
                cb = -0.5f * csum * LOG2E;   // base-2
            }
            cb2[n] = cb;
        }
    }
}

__global__ void fin_k(const float* __restrict__ part, float* __restrict__ out)
{
    int c = threadIdx.x >> 6, l = threadIdx.x & 63;
    if (c < 3) {
        float s = 0.f;
        for (int i = l; i < 256; i += 64) s += part[i * 3 + c];
        #pragma unroll
        for (int d = 1; d < 64; d <<= 1) s += __shfl_xor(s, d);
        if (l == 0) out[c] = s / (float)BB;
    }
}

extern "C" void kernel_launch(void* const* d_in, const int* in_sizes, int n_in,
                              void* d_out, int out_size, void* d_ws, size_t ws_size,
                              hipStream_t stream)
{
    const float* x    = (const float*)d_in[0];
    const float* eps  = (const float*)d_in[1];
    const float* zpre = (const float*)d_in[2];
    const float* ew1  = (const float*)d_in[3];
    const float* eb1  = (const float*)d_in[4];
    const float* ew2  = (const float*)d_in[5];
    const float* eb2  = (const float*)d_in[6];
    const float* ew3  = (const float*)d_in[7];
    const float* eb3  = (const float*)d_in[8];
    const float* dw1  = (const float*)d_in[9];
    const float* db1  = (const float*)d_in[10];
    const float* dw2  = (const float*)d_in[11];
    const float* db2  = (const float*)d_in[12];
    const float* dw3  = (const float*)d_in[13];
    const float* db3  = (const float*)d_in[14];
    float* out = (float*)d_out;

    float* ws   = (float*)d_ws;
    float* part = ws;                        // 256*3
    float* cb2  = part + 768;                // 2048
    unsigned char* ub = (unsigned char*)(cb2 + 2048);
    unsigned char* w1t = ub; ub += 24 * 13 * 1024;
    unsigned char* w2t = ub; ub += 24 * 5 * 1024;
    unsigned char* w3t = ub; ub += 8 * 5 * 1024;
    unsigned char* d1t = ub; ub += 24 * 1 * 1024;
    unsigned char* d2t = ub; ub += 24 * 5 * 1024;
    unsigned char* d3t = ub; ub += 56 * 5 * 1024;
    unsigned char* G   = ub; ub += 128 * 1 * 1024;

    dim3 blk(256);
    prep_k<<<dim3(78, 7), blk, 0, stream>>>(ew1, ew2, ew3, dw1, dw2, dw3, zpre,
                                            w1t, w2t, w3t, d1t, d2t, d3t, G, cb2);
    fused_k<<<256, 1024, 0, stream>>>(x, w1t, eb1, w2t, eb2, w3t, eb3,
                                      d1t, db1, d2t, db2, d3t, db3, G, cb2, eps, part);
    fin_k<<<1, 256, 0, stream>>>(part, out);
}

// Round 26
// 51.177 us; speedup vs baseline: 1.1169x; 1.1169x over previous
//
#include <hip/hip_runtime.h>
#include <hip/hip_bf16.h>
#include <hip/hip_fp8.h>
#include <math.h>

#define BB 8192
#define XD 784
#define ZD 10
#define KK 2000
#define HH 300

typedef unsigned char uchar16 __attribute__((ext_vector_type(16)));
typedef long lng2 __attribute__((ext_vector_type(2)));
typedef float f32x4 __attribute__((ext_vector_type(4)));

__device__ __forceinline__ float sp_(float x) {
    return fmaxf(x, 0.f) + __logf(1.f + __expf(-fabsf(x)));
}
__device__ __forceinline__ float elu_(float x) { return x > 0.f ? x : __expf(x) - 1.f; }
__device__ __forceinline__ unsigned char f8_(float v) {
    __hip_fp8_e4m3 t(v);
    return (unsigned char)t.__x;
}
__device__ __forceinline__ uchar16 ld16_(const unsigned char* p) {
    return *reinterpret_cast<const uchar16*>(p);
}
// fp8 MFMA over one 16B chunk pair (K=64)
__device__ __forceinline__ void mm64(f32x4& acc, uchar16 a, uchar16 b) {
    lng2 la = __builtin_bit_cast(lng2, a);
    lng2 lb = __builtin_bit_cast(lng2, b);
    acc = __builtin_amdgcn_mfma_f32_16x16x32_fp8_fp8(la[0], lb[0], acc, 0, 0, 0);
    acc = __builtin_amdgcn_mfma_f32_16x16x32_fp8_fp8(la[1], lb[1], acc, 0, 0, 0);
}
// fp8 fragment-major byte index: chunk base + element (row<16, k)
__device__ __forceinline__ int fpi_(int chunk, int row, int k) {
    return ((chunk + (k >> 6)) * 64 + row + (((k >> 3) & 3) << 4)) * 16
           + (k & 7) + (((k >> 5) & 1) << 3);
}

// ---------------------------------------------------------------------------
// 16-wave fp8 register-streamed layer (r23 structure — best verified).
// ---------------------------------------------------------------------------
template<int LMODE, int KP, int NI>
__device__ __forceinline__ void layerRf(
    const int tid,
    const unsigned char* __restrict__ actin,
    const unsigned char* __restrict__ Wt,
    const float* __restrict__ bias,
    unsigned char* __restrict__ actout,
    float* __restrict__ c3L, float* __restrict__ redL,
    const float* __restrict__ xrow, float INV, float OUTS)
{
    const int w = tid >> 6, l = tid & 63;
    const int wl = w & 7, wh = w >> 3;
    const int cl = l & 15, hi = l >> 4, g4 = hi << 2;
    constexpr int KS = KP / 64;
    constexpr int NJ = (NI + 1) / 2;
    constexpr int NP = (NJ + 1) / 2;
    const unsigned char* bsrc = Wt + l * 16;

    float rA[2][4];
    #pragma unroll
    for (int rg = 0; rg < 2; ++rg)
        #pragma unroll
        for (int rr = 0; rr < 4; ++rr) rA[rg][rr] = 0.f;

    #pragma unroll
    for (int p = 0; p < NP; ++p) {
        f32x4 acc[2][2];
        #pragma unroll
        for (int j = 0; j < 2; ++j)
            #pragma unroll
            for (int rg = 0; rg < 2; ++rg) acc[j][rg] = (f32x4){0.f, 0.f, 0.f, 0.f};

        int niC[2], rawv[2];
        #pragma unroll
        for (int j = 0; j < 2; ++j) {
            const int njIdx = 2 * p + j;
            const int raw = (njIdx < NJ) ? (2 * njIdx + wh) : (NI - 1);
            rawv[j] = (njIdx < NJ) ? (2 * njIdx + wh) : NI;
            niC[j] = (raw < NI) ? raw : (NI - 1);
        }

        uchar16 Bb[2][2];
        #pragma unroll
        for (int j = 0; j < 2; ++j)
            if ((2 * p + j) < NJ)
                Bb[0][j] = ld16_(bsrc + (((size_t)(niC[j] * 8 + wl) * KS) << 10));

        #pragma unroll
        for (int ki = 0; ki < KS; ++ki) {
            const int cur = ki & 1, nxt = cur ^ 1;
            if (ki + 1 < KS) {
                #pragma unroll
                for (int j = 0; j < 2; ++j)
                    if ((2 * p + j) < NJ)
                        Bb[nxt][j] = ld16_(bsrc + (((size_t)(niC[j] * 8 + wl) * KS + ki + 1) << 10));
            }
            uchar16 a[2];
            a[0] = ld16_(actin + ((0 * KS + ki) * 64 + l) * 16);
            a[1] = ld16_(actin + ((1 * KS + ki) * 64 + l) * 16);
            #pragma unroll
            for (int j = 0; j < 2; ++j)
                if ((2 * p + j) < NJ)
                    #pragma unroll
                    for (int rg = 0; rg < 2; ++rg)
                        mm64(acc[j][rg], a[rg], Bb[cur][j]);
        }

        #pragma unroll
        for (int j = 0; j < 2; ++j) {
            if ((2 * p + j) >= NJ) continue;   // compile-time dead
            const bool act = rawv[j] < NI;
            const int c = rawv[j] * 128 + wl * 16 + cl;
            if constexpr (LMODE == 0) {
                const float bb = (act && c < HH) ? bias[c] : 0.f;
                #pragma unroll
                for (int rg = 0; rg < 2; ++rg)
                    #pragma unroll
                    for (int rr = 0; rr < 4; ++rr) {
                        float o = (c < HH) ? elu_(acc[j][rg][rr] * INV + bb) : 0.f;
                        if (act && c < 320)
                            actout[fpi_(rg * 5, g4 + rr, c)] = f8_(o * OUTS);
                    }
            } else if constexpr (LMODE == 1) {
                const int cc = wl * 16 + cl;
                if (act && cc < 20) {
                    #pragma unroll
                    for (int rg = 0; rg < 2; ++rg)
                        #pragma unroll
                        for (int rr = 0; rr < 4; ++rr)
                            c3L[(rg * 16 + g4 + rr) * 24 + cc] = acc[j][rg][rr] * INV + bias[cc];
                }
            } else {
                if (act && c < XD) {
                    const float bb = bias[c];
                    #pragma unroll
                    for (int rg = 0; rg < 2; ++rg)
                        #pragma unroll
                        for (int rr = 0; rr < 4; ++rr) {
                            float lv = acc[j][rg][rr] * INV + bb;
                            float xv = xrow[(size_t)(rg * 16 + g4 + rr) * XD + c];
                            rA[rg][rr] += xv * lv - sp_(lv);
                        }
                }
            }
        }
    }

    if constexpr (LMODE == 2) {
        #pragma unroll
        for (int rg = 0; rg < 2; ++rg)
            #pragma unroll
            for (int rr = 0; rr < 4; ++rr) {
                float s = rA[rg][rr];
                s += __shfl_xor(s, 1); s += __shfl_xor(s, 2);
                s += __shfl_xor(s, 4); s += __shfl_xor(s, 8);
                if (cl == 0) redL[(rg * 16 + g4 + rr) * 16 + w] = s;
            }
    }
}

// comp: KP=64 (KS=1), 16 n-tiles; per-lane online logsumexp over nj; c_k from
// fp32 cbias; cross-lane merge at end -> redM/redS[row][16].
__device__ __forceinline__ void layerCf(
    const int tid,
    const unsigned char* __restrict__ fbL,
    const unsigned char* __restrict__ G,
    const float* __restrict__ cbias,
    float* __restrict__ redM, float* __restrict__ redS)
{
    const int w = tid >> 6, l = tid & 63;
    const int wl = w & 7, wh = w >> 3;
    const int cl = l & 15, hi = l >> 4, g4 = hi << 2;
    const unsigned char* bsrc = G + l * 16;

    uchar16 a[2];
    a[0] = ld16_(fbL + (0 * 64 + l) * 16);
    a[1] = ld16_(fbL + (1 * 64 + l) * 16);

    float rA[2][4], rB[2][4];
    #pragma unroll
    for (int rg = 0; rg < 2; ++rg)
        #pragma unroll
        for (int rr = 0; rr < 4; ++rr) { rA[rg][rr] = -1e30f; rB[rg][rr] = 0.f; }

    uchar16 c0 = ld16_(bsrc + (((size_t)(wh * 8 + wl)) << 10));
    #pragma unroll
    for (int nj = 0; nj < 8; ++nj) {
        uchar16 p0 = c0;
        if (nj + 1 < 8)
            p0 = ld16_(bsrc + (((size_t)((2 * (nj + 1) + wh) * 8 + wl)) << 10));
        const int c = ((2 * nj + wh) * 8 + wl) * 16 + cl;
        const float cb = cbias[c];
        f32x4 acc[2];
        #pragma unroll
        for (int rg = 0; rg < 2; ++rg) {
            acc[rg] = (f32x4){0.f, 0.f, 0.f, 0.f};
            mm64(acc[rg], a[rg], c0);
        }
        #pragma unroll
        for (int rg = 0; rg < 2; ++rg)
            #pragma unroll
            for (int rr = 0; rr < 4; ++rr) {
                float v = acc[rg][rr] * (1.f / 256.f) + cb;
                float mx = fmaxf(v, rA[rg][rr]);
                rB[rg][rr] = rB[rg][rr] * __expf(rA[rg][rr] - mx) + __expf(v - mx);
                rA[rg][rr] = mx;
            }
        c0 = p0;
    }
    #pragma unroll
    for (int d = 1; d <= 8; d <<= 1)
        #pragma unroll
        for (int rg = 0; rg < 2; ++rg)
            #pragma unroll
            for (int rr = 0; rr < 4; ++rr) {
                float mo = __shfl_xor(rA[rg][rr], d);
                float so = __shfl_xor(rB[rg][rr], d);
                float M = fmaxf(rA[rg][rr], mo);
                rB[rg][rr] = rB[rg][rr] * __expf(rA[rg][rr] - M) + so * __expf(mo - M);
                rA[rg][rr] = M;
            }
    if (cl == 0) {
        #pragma unroll
        for (int rg = 0; rg < 2; ++rg)
            #pragma unroll
            for (int rr = 0; rr < 4; ++rr) {
                redM[(rg * 16 + g4 + rr) * 16 + w] = rA[rg][rr];
                redS[(rg * 16 + g4 + rr) * 16 + w] = rB[rg][rr];
            }
    }
}

__global__ __launch_bounds__(1024, 1)
void fused_k(const float* __restrict__ xg,
             const unsigned char* __restrict__ w1t, const float* __restrict__ eb1,
             const unsigned char* __restrict__ w2t, const float* __restrict__ eb2,
             const unsigned char* __restrict__ w3t, const float* __restrict__ eb3,
             const unsigned char* __restrict__ d1t, const float* __restrict__ db1,
             const unsigned char* __restrict__ d2t, const float* __restrict__ db2,
             const unsigned char* __restrict__ d3t, const float* __restrict__ db3,
             const unsigned char* __restrict__ G, const float* __restrict__ cbias,
             const float* __restrict__ eps, float* __restrict__ part)
{
    __shared__ __align__(16) unsigned char xsf8[26624];  // 32x832 fp8 frag-major
    __shared__ __align__(16) unsigned char actP[10240];
    __shared__ __align__(16) unsigned char actQ[10240];
    __shared__ __align__(16) unsigned char fbL[2048];
    __shared__ float uredc[1568];

    float* c3L  = uredc;
    float* redM = uredc;
    float* redS = uredc + 512;
    float* redL = uredc + 1024;
    float* lqzL = uredc + 1536;

    const int tid = threadIdx.x;
    const int m0 = blockIdx.x * 32;

    // stage x slab fp32 -> fp8 (x16) into LDS, frag-major [rg*13+kc][lane][16]
    #pragma unroll
    for (int it = 0; it < 2; ++it) {
        const int c = tid + it * 1024;
        if (c < 26 * 64) {
            const int chunk = c >> 6, lane = c & 63;
            const int rg = chunk / 13, kc = chunk % 13;
            const int row = m0 + rg * 16 + (lane & 15);
            const int h2 = lane >> 4;
            uchar16 v;
            #pragma unroll
            for (int half = 0; half < 2; ++half) {
                const int kb = kc * 64 + half * 32 + h2 * 8;
                if (kb + 7 < XD) {
                    float4 f0 = *reinterpret_cast<const float4*>(&xg[(size_t)row * XD + kb]);
                    float4 f1 = *reinterpret_cast<const float4*>(&xg[(size_t)row * XD + kb + 4]);
                    v[half * 8 + 0] = f8_(f0.x * 16.f); v[half * 8 + 1] = f8_(f0.y * 16.f);
                    v[half * 8 + 2] = f8_(f0.z * 16.f); v[half * 8 + 3] = f8_(f0.w * 16.f);
                    v[half * 8 + 4] = f8_(f1.x * 16.f); v[half * 8 + 5] = f8_(f1.y * 16.f);
                    v[half * 8 + 6] = f8_(f1.z * 16.f); v[half * 8 + 7] = f8_(f1.w * 16.f);
                } else {
                    #pragma unroll
                    for (int e = 0; e < 8; ++e) {
                        const int k = kb + e;
                        v[half * 8 + e] = (k < XD) ? f8_(xg[(size_t)row * XD + k] * 16.f) : (unsigned char)0;
                    }
                }
            }
            *reinterpret_cast<uchar16*>(&xsf8[c * 16]) = v;
        }
    }
    // zero ALL of fbL: sizeof(fbL)=2048B = 128 uint4
    if (tid < 128) reinterpret_cast<uint4*>(fbL)[tid] = (uint4){0u, 0u, 0u, 0u};
    __syncthreads();

    layerRf<0, 832, 3>(tid, xsf8, w1t, eb1, actP, nullptr, nullptr, nullptr,
                       1.f / 1024.f, 16.f);
    __syncthreads();
    layerRf<0, 320, 3>(tid, actP, w2t, eb2, actQ, nullptr, nullptr, nullptr,
                       1.f / 1024.f, 16.f);
    __syncthreads();
    layerRf<1, 320, 1>(tid, actQ, w3t, eb3, nullptr, c3L, nullptr, nullptr,
                       1.f / 1024.f, 0.f);
    __syncthreads();

    if (tid < 32) {
        float a = 0.f;
        const int rg = tid >> 4, rl = tid & 15;
        #pragma unroll
        for (int j = 0; j < ZD; ++j) {
            float qm = c3L[tid * 24 + j];
            float qh = c3L[tid * 24 + 10 + j];
            float qv = sp_(qh) + 1e-8f;
            float e  = eps[(size_t)(m0 + tid) * ZD + j];
            float zj = qm + sqrtf(qv) * e;
            fbL[fpi_(rg, rl, j)]      = f8_(zj * zj * 4.f);
            fbL[fpi_(rg, rl, 10 + j)] = f8_(zj * 4.f);
            float d = zj - qm;
            a += __logf(6.283185307179586f * qv) + d * d / qv;
        }
        lqzL[tid] = -0.5f * a;
    }
    __syncthreads();

    layerRf<0, 64, 3>(tid, fbL, d1t, db1, actP, nullptr, nullptr, nullptr,
                      1.f / 64.f, 16.f);
    __syncthreads();
    layerRf<0, 320, 3>(tid, actP, d2t, db2, actQ, nullptr, nullptr, nullptr,
                       1.f / 1024.f, 16.f);
    __syncthreads();
    layerRf<2, 320, 7>(tid, actQ, d3t, db3, nullptr, nullptr, redL,
                       xg + (size_t)m0 * XD, 1.f / 1024.f, 0.f);
    __syncthreads();
    layerCf(tid, fbL, G, cbias, redM, redS);
    __syncthreads();

    if (tid < 32) {
        float M = -1e30f, S = 0.f;
        #pragma unroll
        for (int w16 = 0; w16 < 16; ++w16) {
            float m = redM[tid * 16 + w16], s = redS[tid * 16 + w16];
            float M2 = fmaxf(M, m);
            S = S * __expf(M - M2) + s * __expf(m - M2);
            M = M2;
        }
        float lpz = M + __logf(S) - 7.6009024595420824f;  // log(2000)
        float lpx = 0.f;
        #pragma unroll
        for (int w16 = 0; w16 < 16; ++w16) lpx += redL[tid * 16 + w16];
        float kl = lqzL[tid] - lpz;
        float ne = kl - lpx, re = -lpx;
        #pragma unroll
        for (int d = 1; d <= 16; d <<= 1) {
            ne += __shfl_xor(ne, d); kl += __shfl_xor(kl, d); re += __shfl_xor(re, d);
        }
        if (tid == 0) {
            part[blockIdx.x * 3 + 0] = ne;
            part[blockIdx.x * 3 + 1] = kl;
            part[blockIdx.x * 3 + 2] = re;
        }
    }
}

// ---------------------------------------------------------------------------
// prep (weights only): fp8 fragment-major (scaled); G (x64) + fp32 cbias.
// ---------------------------------------------------------------------------
__global__ __launch_bounds__(256)
void prep_k(const float* __restrict__ ew1, const float* __restrict__ ew2,
            const float* __restrict__ ew3, const float* __restrict__ dw1,
            const float* __restrict__ dw2, const float* __restrict__ dw3,
            const float* __restrict__ zpre,
            unsigned char* __restrict__ w1t, unsigned char* __restrict__ w2t,
            unsigned char* __restrict__ w3t, unsigned char* __restrict__ d1t,
            unsigned char* __restrict__ d2t, unsigned char* __restrict__ d3t,
            unsigned char* __restrict__ G, float* __restrict__ cbias)
{
    const int t = blockIdx.x * 256 + threadIdx.x;
    const int y = blockIdx.y;
    const int lane = t & 63, chunk = t >> 6;
    const int cl = lane & 15, hi = lane >> 4;

    auto genw = [&](const float* W, unsigned char* out, int NT, int KS,
                    int K, int N, float s) {
        if (chunk >= NT * KS) return;
        const int kc = chunk % KS, nt = chunk / KS;
        const int n = nt * 16 + cl;
        uchar16 v;
        #pragma unroll
        for (int e = 0; e < 16; ++e) {
            const int k = kc * 64 + (e >> 3) * 32 + hi * 8 + (e & 7);
            v[e] = f8_((n < N && k < K) ? W[(size_t)k * N + n] * s : 0.f);
        }
        *reinterpret_cast<uchar16*>(&out[(size_t)t * 16]) = v;
    };

    if (y == 0) genw(ew1, w1t, 24, 13, XD, HH, 64.f);
    else if (y == 1) genw(ew2, w2t, 24, 5, HH, HH, 64.f);
    else if (y == 2) genw(ew3, w3t, 8, 5, HH, 2 * ZD, 64.f);
    else if (y == 3) {          // d1t: rows k=10..19 hold dw1 (fb layout), x16
        if (chunk >= 24) return;
        const int n = chunk * 16 + cl;
        uchar16 v;
        #pragma unroll
        for (int e = 0; e < 16; ++e) {
            const int k = (e >> 3) * 32 + hi * 8 + (e & 7);
            float vv = (n < HH && k >= 10 && k < 20) ? dw1[(size_t)(k - 10) * HH + n] * 16.f : 0.f;
            v[e] = f8_(vv);
        }
        *reinterpret_cast<uchar16*>(&d1t[(size_t)t * 16]) = v;
    }
    else if (y == 4) genw(dw2, d2t, 24, 5, HH, HH, 64.f);
    else if (y == 5) genw(dw3, d3t, 56, 5, HH, XD, 64.f);
    else {                      // G x64; fp32 cbias
        if (chunk >= 128) return;
        const int n = chunk * 16 + cl;
        uchar16 v;
        #pragma unroll
        for (int e = 0; e < 16; ++e) {
            const int k = (e >> 3) * 32 + hi * 8 + (e & 7);
            float vv = 0.f;
            if (n < KK) {
                if (k < 10) {
                    float h = zpre[(KK + n) * ZD + k];
                    float vr = sp_(h) + 1e-8f;
                    vv = (-0.5f / vr) * 64.f;
                } else if (k < 20) {
                    float m = zpre[n * ZD + (k - 10)];
                    float h = zpre[(KK + n) * ZD + (k - 10)];
                    float vr = sp_(h) + 1e-8f;
                    vv = (m / vr) * 64.f;
                }
            }
            v[e] = f8_(vv);
        }
        *reinterpret_cast<uchar16*>(&G[(size_t)t * 16]) = v;
        if (hi == 0) {
            float cb = -1e30f;
            if (n < KK) {
                float csum = 0.f;
                #pragma unroll
                for (int j = 0; j < ZD; ++j) {
                    float m = zpre[n * ZD + j];
                    float h = zpre[(KK + n) * ZD + j];
                    float vr = sp_(h) + 1e-8f;
                    csum += __logf(6.283185307179586f * vr) + m * m / vr;
                }
                cb = -0.5f * csum;
            }
            cbias[n] = cb;
        }
    }
}

__global__ void fin_k(const float* __restrict__ part, float* __restrict__ out)
{
    int c = threadIdx.x >> 6, l = threadIdx.x & 63;
    if (c < 3) {
        float s = 0.f;
        for (int i = l; i < 256; i += 64) s += part[i * 3 + c];
        #pragma unroll
        for (int d = 1; d < 64; d <<= 1) s += __shfl_xor(s, d);
        if (l == 0) out[c] = s / (float)BB;
    }
}

extern "C" void kernel_launch(void* const* d_in, const int* in_sizes, int n_in,
                              void* d_out, int out_size, void* d_ws, size_t ws_size,
                              hipStream_t stream)
{
    const float* x    = (const float*)d_in[0];
    const float* eps  = (const float*)d_in[1];
    const float* zpre = (const float*)d_in[2];
    const float* ew1  = (const float*)d_in[3];
    const float* eb1  = (const float*)d_in[4];
    const float* ew2  = (const float*)d_in[5];
    const float* eb2  = (const float*)d_in[6];
    const float* ew3  = (const float*)d_in[7];
    const float* eb3  = (const float*)d_in[8];
    const float* dw1  = (const float*)d_in[9];
    const float* db1  = (const float*)d_in[10];
    const float* dw2  = (const float*)d_in[11];
    const float* db2  = (const float*)d_in[12];
    const float* dw3  = (const float*)d_in[13];
    const float* db3  = (const float*)d_in[14];
    float* out = (float*)d_out;

    float* ws    = (float*)d_ws;
    float* part  = ws;                       // 256*3
    float* cbias = part + 768;               // 2048
    unsigned char* ub = (unsigned char*)(cbias + 2048);
    unsigned char* w1t = ub; ub += 24 * 13 * 1024;
    unsigned char* w2t = ub; ub += 24 * 5 * 1024;
    unsigned char* w3t = ub; ub += 8 * 5 * 1024;
    unsigned char* d1t = ub; ub += 24 * 1 * 1024;
    unsigned char* d2t = ub; ub += 24 * 5 * 1024;
    unsigned char* d3t = ub; ub += 56 * 5 * 1024;
    unsigned char* G   = ub; ub += 128 * 1 * 1024;

    dim3 blk(256);
    prep_k<<<dim3(78, 7), blk, 0, stream>>>(ew1, ew2, ew3, dw1, dw2, dw3, zpre,
                                            w1t, w2t, w3t, d1t, d2t, d3t, G, cbias);
    fused_k<<<256, 1024, 0, stream>>>(x, w1t, eb1, w2t, eb2, w3t, eb3,
                                      d1t, db1, d2t, db2, d3t, db3, G, cbias, eps, part);
    fin_k<<<1, 256, 0, stream>>>(part, out);
}